// Round 9
// baseline (106.433 us; speedup 1.0000x reference)
//
#include <hip/hip_runtime.h>
#include <hip/hip_bf16.h>
#include <stdint.h>
#include <stddef.h>

// ---------------------------------------------------------------------------
// FixedEmbedderNN — round 9: conflict-free LDS gather + lean kernel split.
//  xprep : per row, pack 20 categorical codes as u8[32] and numeric MFMA
//          B-fragment as bf16[32] (k<20 -> x, k==20 -> 1, else 0).
//  gatherk: 256 blocks (1/CU) x 512 thr. For each column half (staged 125KB
//          in LDS, two sequential passes): lane=(row r8=lane>>3, slot s=lane&7)
//          reads ONE 16B slot per feature -> per instruction all 8 slots of 8
//          rows are covered => bank-perfect ds_read_b128 (no rotation needed).
//          acc(8 cols) += 20 features; store bf16 16B to h1c (slot-major),
//          placed in d_out's 512B row slot (race-free in-place aliasing).
//  tailk : numeric MFMA emits DIRECTLY in the 8-run a2 layout via a writer-
//          permuted a1p (col = 32(t>>1)+8(p>>2)+4(t&1)+(p&3)); add gathered
//          bf16 chunks; LN0 stats wave-local; then proven GEMM2'->LN1->GEMM3'.
//  Layouts: tcatp[2][20][50][64]u16, row pos 8s+i <-> col 16(4h+2(s&1)+(i>>2))
//          +4(s>>1)+(i&3). h1c[row][128]u16 at stride 256 u16 (first half).
// ---------------------------------------------------------------------------

typedef __attribute__((ext_vector_type(8))) short short8;
typedef __attribute__((ext_vector_type(4))) float f32x4;
typedef __attribute__((ext_vector_type(2))) uint32_t uint32x2;

#define LN_EPS 1e-5f

__device__ __forceinline__ float bflo(uint32_t u){ union{uint32_t u;float f;} c; c.u = u<<16; return c.f; }
__device__ __forceinline__ float bfhi(uint32_t u){ union{uint32_t u;float f;} c; c.u = u&0xffff0000u; return c.f; }
__device__ __forceinline__ uint16_t f2bf(float f){
  union{ __hip_bfloat16 h; uint16_t u; } c; c.h = __float2bfloat16(f); return c.u;
}
__device__ __forceinline__ uint32_t pkbf(float lo, float hi){
  return (uint32_t)f2bf(lo) | ((uint32_t)f2bf(hi)<<16);
}

// ---------------- xprep: pack idx bytes + numeric bf16 frags ----------------
__global__ __launch_bounds__(256) void xprep(
    const float* __restrict__ x,
    uint8_t* __restrict__ idxb,    // [98304][32] u8 (20 used)
    uint16_t* __restrict__ nf)     // [98304][32] bf16 (k<20: x_num, 20:1, else 0)
{
  const int row = blockIdx.x*256 + threadIdx.x;
  const float* xr = x + (size_t)row*40;
  const f32x4 c0 = *reinterpret_cast<const f32x4*>(xr);
  const f32x4 c1 = *reinterpret_cast<const f32x4*>(xr + 4);
  const f32x4 c2 = *reinterpret_cast<const f32x4*>(xr + 8);
  const f32x4 c3 = *reinterpret_cast<const f32x4*>(xr + 12);
  const f32x4 c4 = *reinterpret_cast<const f32x4*>(xr + 16);
  uint4 I0, I1;
  I0.x = (uint32_t)c0[0] | ((uint32_t)c0[1]<<8) | ((uint32_t)c0[2]<<16) | ((uint32_t)c0[3]<<24);
  I0.y = (uint32_t)c1[0] | ((uint32_t)c1[1]<<8) | ((uint32_t)c1[2]<<16) | ((uint32_t)c1[3]<<24);
  I0.z = (uint32_t)c2[0] | ((uint32_t)c2[1]<<8) | ((uint32_t)c2[2]<<16) | ((uint32_t)c2[3]<<24);
  I0.w = (uint32_t)c3[0] | ((uint32_t)c3[1]<<8) | ((uint32_t)c3[2]<<16) | ((uint32_t)c3[3]<<24);
  I1.x = (uint32_t)c4[0] | ((uint32_t)c4[1]<<8) | ((uint32_t)c4[2]<<16) | ((uint32_t)c4[3]<<24);
  I1.y = 0; I1.z = 0; I1.w = 0;
  uint4* ip = reinterpret_cast<uint4*>(idxb + (size_t)row*32);
  ip[0] = I0; ip[1] = I1;

  const f32x4 n0 = *reinterpret_cast<const f32x4*>(xr + 20);
  const f32x4 n1 = *reinterpret_cast<const f32x4*>(xr + 24);
  const f32x4 n2 = *reinterpret_cast<const f32x4*>(xr + 28);
  const f32x4 n3 = *reinterpret_cast<const f32x4*>(xr + 32);
  const f32x4 n4 = *reinterpret_cast<const f32x4*>(xr + 36);
  uint4 N0, N1, N2, N3;
  N0.x = pkbf(n0[0], n0[1]); N0.y = pkbf(n0[2], n0[3]);
  N0.z = pkbf(n1[0], n1[1]); N0.w = pkbf(n1[2], n1[3]);
  N1.x = pkbf(n2[0], n2[1]); N1.y = pkbf(n2[2], n2[3]);
  N1.z = pkbf(n3[0], n3[1]); N1.w = pkbf(n3[2], n3[3]);
  N2.x = pkbf(n4[0], n4[1]); N2.y = pkbf(n4[2], n4[3]);
  N2.z = pkbf(1.0f, 0.0f);   N2.w = 0;
  N3.x = 0; N3.y = 0; N3.z = 0; N3.w = 0;
  uint4* np = reinterpret_cast<uint4*>(nf + (size_t)row*32);
  np[0] = N0; np[1] = N1; np[2] = N2; np[3] = N3;
}

// ---------------- precompute kernel 1 (no deps) ----------------
__global__ __launch_bounds__(128) void pre1(
    const float* __restrict__ W_num, const float* __restrict__ b_num,
    const float* __restrict__ W_in,  const float* __restrict__ b_in,
    const float* __restrict__ W1,    const float* __restrict__ b1,
    const float* __restrict__ W2,    const float* __restrict__ b2,
    const float* __restrict__ W_out, const float* __restrict__ b_out,
    const float* __restrict__ ln_g,  const float* __restrict__ ln_b,
    float* __restrict__ WLf,    // [2][128][128]
    float* __restrict__ Bnum,   // [21][128]
    float* __restrict__ bfold,  // [2][128]
    uint16_t* __restrict__ woutp, // Wout' transposed pack
    float* __restrict__ boutp)    // bout' permuted [g*32+t*4+r]
{
  const int b = blockIdx.x, j = threadIdx.x;
  if (b < 256) {                       // WL = W1@W2 per layer
    const int l = b >> 7, k = b & 127;
    const float* w1r = W1 + (l*128 + k)*256;
    const float* w2  = W2 + l*256*128;
    float s = 0.f;
    for (int m = 0; m < 256; m++) s = fmaf(w1r[m], w2[m*128 + j], s);
    WLf[(l*128 + k)*128 + j] = s;
  } else if (b < 277) {                // Bnum rows
    const int r = b - 256;
    if (r < 20) {
      const float* wn = W_num + r*32;
      const float* wi = W_in + (size_t)(20 + r)*32*128;
      float s = 0.f;
      for (int e = 0; e < 32; e++) s = fmaf(wn[e], wi[e*128 + j], s);
      Bnum[r*128 + j] = s;
    } else {
      float s = b_in[j];
      for (int f = 0; f < 20; f++) {
        const float* bn = b_num + f*32;
        const float* wi = W_in + (size_t)(20 + f)*32*128;
        for (int e = 0; e < 32; e++) s = fmaf(bn[e], wi[e*128 + j], s);
      }
      Bnum[20*128 + j] = s;
    }
  } else if (b < 279) {                // bfold = b1@W2 + b2
    const int l = b - 277;
    const float* b1r = b1 + l*256;
    const float* w2  = W2 + l*256*128;
    float s = b2[l*128 + j];
    for (int k = 0; k < 256; k++) s = fmaf(b1r[k], w2[k*128 + j], s);
    bfold[l*128 + j] = s;
  } else if (b < 311) {                // woutp: Wout' = diag(g1)@W_out, transposed A-pack
    const int p = b - 279, t = p >> 2, ks = p & 3;
    const int lane = j & 63, rep = j >> 6;
    const int col = 16*t + (lane & 15);
    for (int ii = 0; ii < 4; ii++) {
      const int i = rep*4 + ii;
      const int k = 32*ks + 8*(lane >> 4) + i;
      woutp[((t*4 + ks)*64 + lane)*8 + i] = f2bf(ln_g[128 + k] * W_out[k*128 + col]);
    }
  } else {                             // boutp (permuted): b1n@W_out + b_out
    const int t = (j >> 2) & 7, g = j >> 5, r = j & 3;
    const int col = 16*t + 4*g + r;
    float s = b_out[col];
    for (int k = 0; k < 128; k++) s = fmaf(ln_b[128 + k], W_out[k*128 + col], s);
    boutp[j] = s;
  }
}

// ---------------- precompute kernel 2 (depends on pre1) ----------------
__global__ __launch_bounds__(128) void pre2(
    const float* __restrict__ emb, const float* __restrict__ W_in,
    const float* __restrict__ ln_g, const float* __restrict__ ln_b,
    const float* __restrict__ WLf, const float* __restrict__ Bnum,
    const float* __restrict__ bfold,
    uint16_t* __restrict__ tcatp, // [2][20][50][64] bf16 slot-major (natural)
    uint16_t* __restrict__ wl2p,  // WL1' transposed pack
    float* __restrict__ bf1p,     // bf1' permuted
    uint16_t* __restrict__ a1p)   // A1^T pack, 8-run col map
{
  const int b = blockIdx.x, j = threadIdx.x;
  __shared__ float sh[128];
  if (b < 1000) {                      // Tcat1 = emb@W_in_slice@WL_0, slot-major store
    const int f = b / 50, c = b % 50;
    const float* e  = emb + (f*50 + c)*32;
    const float* wi = W_in + (size_t)f*32*128;
    float s = 0.f;
    for (int k = 0; k < 32; k++) s = fmaf(e[k], wi[k*128 + j], s);
    sh[j] = s;
    __syncthreads();
    float s2 = 0.f;
    for (int k = 0; k < 128; k++) s2 = fmaf(sh[k], WLf[k*128 + j], s2);
    // col j = 16t+4g+r -> h=t>>2, jj=t&3, slot=2g+(jj>>1), pos=slot*8+(jj&1)*4+r
    const int t = j >> 4, g = (j >> 2) & 3, r = j & 3;
    const int h = t >> 2, jj = t & 3;
    const int slot = 2*g + (jj >> 1);
    tcatp[((h*20 + f)*50 + c)*64 + slot*8 + (jj & 1)*4 + r] = f2bf(s2);
  } else if (b < 1032) {               // wl2p: WL1' = diag(g0)@WL_1, transposed A-pack
    const int p = b - 1000, t = p >> 2, ks = p & 3;
    const int lane = j & 63, rep = j >> 6;
    const int col = 16*t + (lane & 15);
    const float* wl1 = WLf + 16384;
    for (int ii = 0; ii < 4; ii++) {
      const int i = rep*4 + ii;
      const int k = 32*ks + 8*(lane >> 4) + i;
      wl2p[((t*4 + ks)*64 + lane)*8 + i] = f2bf(ln_g[k] * wl1[k*128 + col]);
    }
  } else if (b == 1032) {              // bf1p (permuted): b0@WL_1 + bfold_1
    const int t = (j >> 2) & 7, g = j >> 5, r = j & 3;
    const int col = 16*t + 4*g + r;
    const float* wl1 = WLf + 16384;
    float s = bfold[128 + col];
    for (int k = 0; k < 128; k++) s = fmaf(ln_b[k], wl1[k*128 + col], s);
    bf1p[j] = s;
  } else {                             // a1p with 8-run col map:
    // tile t, frag pos p=lane&15 -> col = 32(t>>1) + 8(p>>2) + 4(t&1) + (p&3)
    const int t = b - 1033;
    const int lane = j & 63, rep = j >> 6;
    const int p = lane & 15;
    const int col = 32*(t >> 1) + 8*(p >> 2) + 4*(t & 1) + (p & 3);
    for (int ii = 0; ii < 4; ii++) {
      const int i = rep*4 + ii;
      const int k = 8*(lane >> 4) + i;
      float v = 0.f;
      if (k <= 20) {
        if (k == 20) v = bfold[col];
        for (int m = 0; m < 128; m++) v = fmaf(Bnum[k*128 + m], WLf[m*128 + col], v);
      }
      a1p[(t*64 + lane)*8 + i] = f2bf(v);
    }
  }
}

// ---------------- gatherk: bank-perfect LDS gather ----------------
// 256 blocks (1/CU) x 512 thr; block = 384 rows; two sequential half passes.
__global__ __launch_bounds__(512, 1) void gatherk(
    const uint8_t* __restrict__ idxb,
    const uint16_t* __restrict__ tcatp,
    uint16_t* __restrict__ h1c)      // = (uint16_t*)d_out; row stride 256 u16
{
  __shared__ uint4 tbl4[8000];                 // 128000 B half table
  const int tid = threadIdx.x, lane = tid & 63, w = tid >> 6;
  const int r8 = lane >> 3, s = lane & 7;
  const char* tbl = (const char*)tbl4;
  const int rowbase0 = blockIdx.x*384 + w*48;

  for (int h = 0; h < 2; h++) {
    {  // stage half h (linear, conflict-free)
      const uint4* src = reinterpret_cast<const uint4*>(tcatp) + h*8000;
      for (int i = tid; i < 8000; i += 512) tbl4[i] = src[i];
    }
    __syncthreads();

    for (int gr = 0; gr < 6; gr++) {
      const int row = rowbase0 + gr*8 + r8;
      const uint4 I0 = *reinterpret_cast<const uint4*>(idxb + (size_t)row*32);
      const uint4 I1 = *reinterpret_cast<const uint4*>(idxb + (size_t)row*32 + 16);
      const uint32_t iw[5] = {I0.x, I0.y, I0.z, I0.w, I1.x};

      uint4 b[20];
      #pragma unroll
      for (int f = 0; f < 20; f++) {
        const int idx = (int)((iw[f >> 2] >> (8*(f & 3))) & 0xffu);
        b[f] = *reinterpret_cast<const uint4*>(tbl + (f*50 + idx)*128 + s*16);
      }
      f32x4 a0 = {0.f,0.f,0.f,0.f}, a1 = {0.f,0.f,0.f,0.f};
      #pragma unroll
      for (int f = 0; f < 20; f++) {
        a0[0] += bflo(b[f].x); a0[1] += bfhi(b[f].x);
        a0[2] += bflo(b[f].y); a0[3] += bfhi(b[f].y);
        a1[0] += bflo(b[f].z); a1[1] += bfhi(b[f].z);
        a1[2] += bflo(b[f].w); a1[3] += bfhi(b[f].w);
      }
      const uint4 o = { pkbf(a0[0], a0[1]), pkbf(a0[2], a0[3]),
                        pkbf(a1[0], a1[1]), pkbf(a1[2], a1[3]) };
      *reinterpret_cast<uint4*>(h1c + (size_t)row*256 + 64*h + 8*s) = o;
    }
    __syncthreads();   // all reads of this half done before re-staging
  }
}

// ---------------- tailk: numeric MFMA + LN0 + GEMM tail ----------------
// 1536 blocks x 256 thr (4 waves); wave owns 16 rows; in-place on d_out.
__global__ __launch_bounds__(256, 4) void tailk(
    const uint16_t* h1c,               // aliases out
    const uint16_t* __restrict__ nf,
    const uint16_t* __restrict__ a1p,
    const uint16_t* __restrict__ wl2p,
    const uint16_t* __restrict__ woutp,
    const float* __restrict__ bf1p,
    const float* __restrict__ boutp,
    float* out)
{
  __shared__ __align__(16) uint16_t hbuf[4*16*136];
  const int tid = threadIdx.x, lane = tid & 63, w = tid >> 6;
  const int g = lane >> 4, c16 = lane & 15;
  const int row = blockIdx.x*64 + w*16 + c16;
  uint16_t* hb = hbuf + w*16*136;

  // numeric fold: acc[t=2ks+hl][r] = cols 32ks+8g+4hl+r (8-run a1p map)
  const short8 xf = *reinterpret_cast<const short8*>(nf + (size_t)row*32 + 8*g);
  f32x4 acc[8];
  #pragma unroll
  for (int t = 0; t < 8; t++) {
    const short8 af = *reinterpret_cast<const short8*>(a1p + (t*64 + lane)*8);
    acc[t] = __builtin_amdgcn_mfma_f32_16x16x32_bf16(af, xf, (f32x4){0.f,0.f,0.f,0.f}, 0, 0, 0);
  }

  // add gathered categorical part (slot-major bf16 h1c)
  const uint16_t* h1row = h1c + (size_t)row*256;
  #pragma unroll
  for (int ks = 0; ks < 4; ks++)
    #pragma unroll
    for (int hl = 0; hl < 2; hl++) {
      const int inner = 8*g + 4*hl;
      const int tc = 2*ks + (inner >> 4);
      const int gc = (inner & 15) >> 2;
      const int jj = tc & 3;
      const int P = 64*(tc >> 2) + 8*(2*gc + (jj >> 1)) + 4*(jj & 1);
      const uint2 u = *reinterpret_cast<const uint2*>(h1row + P);
      const int t = 2*ks + hl;
      acc[t][0] += bflo(u.x); acc[t][1] += bfhi(u.x);
      acc[t][2] += bflo(u.y); acc[t][3] += bfhi(u.y);
    }

  // LN0 (gamma/beta folded downstream): stats via sum + sumsq, 4 lanes/row
  float s = 0.f, q = 0.f;
  #pragma unroll
  for (int t = 0; t < 8; t++)
    #pragma unroll
    for (int r = 0; r < 4; r++) { const float v = acc[t][r]; s += v; q = fmaf(v, v, q); }
  s += __shfl_xor(s, 16); s += __shfl_xor(s, 32);
  q += __shfl_xor(q, 16); q += __shfl_xor(q, 32);
  const float mu = s * (1.f/128.f);
  const float rs = rsqrtf(q*(1.f/128.f) - mu*mu + LN_EPS);

  // pack a2: a2[ks] elem (4hl+r) = z(col 32ks+8g+4hl+r)
  short8 a2[4];
  #pragma unroll
  for (int ks = 0; ks < 4; ks++) {
    uint32_t* aw = (uint32_t*)&a2[ks];
    aw[0] = pkbf((acc[2*ks][0]-mu)*rs,   (acc[2*ks][1]-mu)*rs);
    aw[1] = pkbf((acc[2*ks][2]-mu)*rs,   (acc[2*ks][3]-mu)*rs);
    aw[2] = pkbf((acc[2*ks+1][0]-mu)*rs, (acc[2*ks+1][1]-mu)*rs);
    aw[3] = pkbf((acc[2*ks+1][2]-mu)*rs, (acc[2*ks+1][3]-mu)*rs);
  }

  // GEMM2': acc2 = z1 @ WL1' (+bf1')
  f32x4 acc2[8];
  #pragma unroll
  for (int t = 0; t < 8; t++) {
    acc2[t] = *reinterpret_cast<const f32x4*>(bf1p + g*32 + t*4);
    #pragma unroll
    for (int ks = 0; ks < 4; ks++) {
      const short8 wf = *reinterpret_cast<const short8*>(wl2p + ((t*4 + ks)*64 + lane)*8);
      acc2[t] = __builtin_amdgcn_mfma_f32_16x16x32_bf16(wf, a2[ks], acc2[t], 0, 0, 0);
    }
  }

  // LN1
  float s2 = 0.f, q2 = 0.f;
  #pragma unroll
  for (int t = 0; t < 8; t++)
    #pragma unroll
    for (int r = 0; r < 4; r++) { const float v = acc2[t][r]; s2 += v; q2 = fmaf(v, v, q2); }
  s2 += __shfl_xor(s2, 16); s2 += __shfl_xor(s2, 32);
  q2 += __shfl_xor(q2, 16); q2 += __shfl_xor(q2, 32);
  const float mu2 = s2 * (1.f/128.f);
  const float rs2 = rsqrtf(q2*(1.f/128.f) - mu2*mu2 + LN_EPS);

  #pragma unroll
  for (int t = 0; t < 8; t++) {
    const uint32x2 v = { pkbf((acc2[t][0]-mu2)*rs2, (acc2[t][1]-mu2)*rs2),
                         pkbf((acc2[t][2]-mu2)*rs2, (acc2[t][3]-mu2)*rs2) };
    *reinterpret_cast<uint32x2*>(hb + c16*136 + 16*t + 4*g) = v;
  }
  asm volatile("s_waitcnt lgkmcnt(0)" ::: "memory");

  // GEMM3': out = z2 @ Wout' + bout'  (reads of h1c drained before stores)
  short8 a3[4];
  #pragma unroll
  for (int ks = 0; ks < 4; ks++)
    a3[ks] = *reinterpret_cast<const short8*>(hb + c16*136 + 32*ks + 8*g);
  float* orow = out + (size_t)row*128;
  #pragma unroll
  for (int t = 0; t < 8; t++) {
    f32x4 a3c = *reinterpret_cast<const f32x4*>(boutp + g*32 + t*4);
    #pragma unroll
    for (int ks = 0; ks < 4; ks++) {
      const short8 wf = *reinterpret_cast<const short8*>(woutp + ((t*4 + ks)*64 + lane)*8);
      a3c = __builtin_amdgcn_mfma_f32_16x16x32_bf16(wf, a3[ks], a3c, 0, 0, 0);
    }
    *reinterpret_cast<f32x4*>(orow + 16*t + 4*g) = a3c;
  }
}

// ---------------- launcher ----------------
extern "C" void kernel_launch(void* const* d_in, const int* in_sizes, int n_in,
                              void* d_out, int out_size, void* d_ws, size_t ws_size,
                              hipStream_t stream)
{
  const float* x     = (const float*)d_in[0];
  const float* emb   = (const float*)d_in[1];
  const float* W_num = (const float*)d_in[2];
  const float* b_num = (const float*)d_in[3];
  const float* W_in  = (const float*)d_in[4];
  const float* b_in  = (const float*)d_in[5];
  const float* W1    = (const float*)d_in[6];
  const float* b1    = (const float*)d_in[7];
  const float* W2    = (const float*)d_in[8];
  const float* b2    = (const float*)d_in[9];
  const float* ln_g  = (const float*)d_in[10];
  const float* ln_b  = (const float*)d_in[11];
  const float* W_out = (const float*)d_in[12];
  const float* b_out = (const float*)d_in[13];
  float* out = (float*)d_out;

  char* ws = (char*)d_ws;
  float*    WLf   = (float*)(ws + 0);          // 131072 B
  float*    Bnum  = (float*)(ws + 131072);     //  10752 B
  float*    bfold = (float*)(ws + 141824);     //   1024 B
  uint16_t* tcatp = (uint16_t*)(ws + 142848);  // 256000 B
  uint16_t* wl2p  = (uint16_t*)(ws + 398848);  //  32768 B
  uint16_t* woutp = (uint16_t*)(ws + 431616);  //  32768 B
  uint16_t* a1p   = (uint16_t*)(ws + 464384);  //   8192 B
  float*    bf1p  = (float*)(ws + 472576);     //    512 B
  float*    boutp = (float*)(ws + 473088);     //    512 B
  uint8_t*  idxb  = (uint8_t*)(ws + 473600);   // 3145728 B
  uint16_t* nf    = (uint16_t*)(ws + 3619328); // 6291456 B

  xprep<<<dim3(384), dim3(256), 0, stream>>>(x, idxb, nf);
  pre1<<<dim3(312), dim3(128), 0, stream>>>(W_num, b_num, W_in, b_in, W1, b1, W2, b2,
                                            W_out, b_out, ln_g, ln_b,
                                            WLf, Bnum, bfold, woutp, boutp);
  pre2<<<dim3(1041), dim3(128), 0, stream>>>(emb, W_in, ln_g, ln_b, WLf, Bnum, bfold,
                                             tcatp, wl2p, bf1p, a1p);
  gatherk<<<dim3(256), dim3(512), 0, stream>>>(idxb, tcatp, (uint16_t*)d_out);
  tailk<<<dim3(1536), dim3(256), 0, stream>>>((const uint16_t*)d_out, nf, a1p,
                                              wl2p, woutp, bf1p, boutp, out);
}

// Round 10
// 96.399 us; speedup vs baseline: 1.1041x; 1.1041x over previous
//
#include <hip/hip_runtime.h>
#include <hip/hip_bf16.h>
#include <stdint.h>
#include <stddef.h>

// ---------------------------------------------------------------------------
// FixedEmbedderNN — round 10: single fused main kernel, 1 block/CU.
//  LDS union (162,816 B):
//    phase A/B: [0,128000) half-table   + [128000,162816) hstate (128x136 u16)
//    phase C  : [0,32768) wl2l, [32768,65536) wol, [65536,73728) a1l,
//               [73728,74240) bf1l, [74240,74752) boll,
//               [74752,109568) hbuf (8 waves x 4352B)   -- hstate persists.
//  Flow: stage tbl h0 | gather A -> hstate | stage h1 | gather B -> hstate |
//        stage weights | r9-tail per wave (numeric MFMA + hstate add + LN0 +
//        GEMM2' + LN1 + GEMM3') -> out.
//  All mappings identical to round 9 (verified passing): tcatp slot-major
//  [2][20][50][64], a1p 8-run col map, tail P-formula, hstate = h1c layout
//  with stride 136 u16 instead of 256.
// ---------------------------------------------------------------------------

typedef __attribute__((ext_vector_type(8))) short short8;
typedef __attribute__((ext_vector_type(4))) float f32x4;
typedef __attribute__((ext_vector_type(2))) uint32_t uint32x2;

#define LN_EPS 1e-5f

__device__ __forceinline__ float bflo(uint32_t u){ union{uint32_t u;float f;} c; c.u = u<<16; return c.f; }
__device__ __forceinline__ float bfhi(uint32_t u){ union{uint32_t u;float f;} c; c.u = u&0xffff0000u; return c.f; }
__device__ __forceinline__ uint16_t f2bf(float f){
  union{ __hip_bfloat16 h; uint16_t u; } c; c.h = __float2bfloat16(f); return c.u;
}
__device__ __forceinline__ uint32_t pkbf(float lo, float hi){
  return (uint32_t)f2bf(lo) | ((uint32_t)f2bf(hi)<<16);
}

// ---------------- xprep: pack idx bytes + numeric bf16 frags ----------------
__global__ __launch_bounds__(256) void xprep(
    const float* __restrict__ x,
    uint8_t* __restrict__ idxb,    // [98304][32] u8 (20 used)
    uint16_t* __restrict__ nf)     // [98304][32] bf16 (k<20: x_num, 20:1, else 0)
{
  const int row = blockIdx.x*256 + threadIdx.x;
  const float* xr = x + (size_t)row*40;
  const f32x4 c0 = *reinterpret_cast<const f32x4*>(xr);
  const f32x4 c1 = *reinterpret_cast<const f32x4*>(xr + 4);
  const f32x4 c2 = *reinterpret_cast<const f32x4*>(xr + 8);
  const f32x4 c3 = *reinterpret_cast<const f32x4*>(xr + 12);
  const f32x4 c4 = *reinterpret_cast<const f32x4*>(xr + 16);
  uint4 I0, I1;
  I0.x = (uint32_t)c0[0] | ((uint32_t)c0[1]<<8) | ((uint32_t)c0[2]<<16) | ((uint32_t)c0[3]<<24);
  I0.y = (uint32_t)c1[0] | ((uint32_t)c1[1]<<8) | ((uint32_t)c1[2]<<16) | ((uint32_t)c1[3]<<24);
  I0.z = (uint32_t)c2[0] | ((uint32_t)c2[1]<<8) | ((uint32_t)c2[2]<<16) | ((uint32_t)c2[3]<<24);
  I0.w = (uint32_t)c3[0] | ((uint32_t)c3[1]<<8) | ((uint32_t)c3[2]<<16) | ((uint32_t)c3[3]<<24);
  I1.x = (uint32_t)c4[0] | ((uint32_t)c4[1]<<8) | ((uint32_t)c4[2]<<16) | ((uint32_t)c4[3]<<24);
  I1.y = 0; I1.z = 0; I1.w = 0;
  uint4* ip = reinterpret_cast<uint4*>(idxb + (size_t)row*32);
  ip[0] = I0; ip[1] = I1;

  const f32x4 n0 = *reinterpret_cast<const f32x4*>(xr + 20);
  const f32x4 n1 = *reinterpret_cast<const f32x4*>(xr + 24);
  const f32x4 n2 = *reinterpret_cast<const f32x4*>(xr + 28);
  const f32x4 n3 = *reinterpret_cast<const f32x4*>(xr + 32);
  const f32x4 n4 = *reinterpret_cast<const f32x4*>(xr + 36);
  uint4 N0, N1, N2, N3;
  N0.x = pkbf(n0[0], n0[1]); N0.y = pkbf(n0[2], n0[3]);
  N0.z = pkbf(n1[0], n1[1]); N0.w = pkbf(n1[2], n1[3]);
  N1.x = pkbf(n2[0], n2[1]); N1.y = pkbf(n2[2], n2[3]);
  N1.z = pkbf(n3[0], n3[1]); N1.w = pkbf(n3[2], n3[3]);
  N2.x = pkbf(n4[0], n4[1]); N2.y = pkbf(n4[2], n4[3]);
  N2.z = pkbf(1.0f, 0.0f);   N2.w = 0;
  N3.x = 0; N3.y = 0; N3.z = 0; N3.w = 0;
  uint4* np = reinterpret_cast<uint4*>(nf + (size_t)row*32);
  np[0] = N0; np[1] = N1; np[2] = N2; np[3] = N3;
}

// ---------------- precompute kernel 1 (no deps) ----------------
__global__ __launch_bounds__(128) void pre1(
    const float* __restrict__ W_num, const float* __restrict__ b_num,
    const float* __restrict__ W_in,  const float* __restrict__ b_in,
    const float* __restrict__ W1,    const float* __restrict__ b1,
    const float* __restrict__ W2,    const float* __restrict__ b2,
    const float* __restrict__ W_out, const float* __restrict__ b_out,
    const float* __restrict__ ln_g,  const float* __restrict__ ln_b,
    float* __restrict__ WLf,    // [2][128][128]
    float* __restrict__ Bnum,   // [21][128]
    float* __restrict__ bfold,  // [2][128]
    uint16_t* __restrict__ woutp, // Wout' transposed pack
    float* __restrict__ boutp)    // bout' permuted [g*32+t*4+r]
{
  const int b = blockIdx.x, j = threadIdx.x;
  if (b < 256) {                       // WL = W1@W2 per layer
    const int l = b >> 7, k = b & 127;
    const float* w1r = W1 + (l*128 + k)*256;
    const float* w2  = W2 + l*256*128;
    float s = 0.f;
    for (int m = 0; m < 256; m++) s = fmaf(w1r[m], w2[m*128 + j], s);
    WLf[(l*128 + k)*128 + j] = s;
  } else if (b < 277) {                // Bnum rows
    const int r = b - 256;
    if (r < 20) {
      const float* wn = W_num + r*32;
      const float* wi = W_in + (size_t)(20 + r)*32*128;
      float s = 0.f;
      for (int e = 0; e < 32; e++) s = fmaf(wn[e], wi[e*128 + j], s);
      Bnum[r*128 + j] = s;
    } else {
      float s = b_in[j];
      for (int f = 0; f < 20; f++) {
        const float* bn = b_num + f*32;
        const float* wi = W_in + (size_t)(20 + f)*32*128;
        for (int e = 0; e < 32; e++) s = fmaf(bn[e], wi[e*128 + j], s);
      }
      Bnum[20*128 + j] = s;
    }
  } else if (b < 279) {                // bfold = b1@W2 + b2
    const int l = b - 277;
    const float* b1r = b1 + l*256;
    const float* w2  = W2 + l*256*128;
    float s = b2[l*128 + j];
    for (int k = 0; k < 256; k++) s = fmaf(b1r[k], w2[k*128 + j], s);
    bfold[l*128 + j] = s;
  } else if (b < 311) {                // woutp: Wout' = diag(g1)@W_out, transposed A-pack
    const int p = b - 279, t = p >> 2, ks = p & 3;
    const int lane = j & 63, rep = j >> 6;
    const int col = 16*t + (lane & 15);
    for (int ii = 0; ii < 4; ii++) {
      const int i = rep*4 + ii;
      const int k = 32*ks + 8*(lane >> 4) + i;
      woutp[((t*4 + ks)*64 + lane)*8 + i] = f2bf(ln_g[128 + k] * W_out[k*128 + col]);
    }
  } else {                             // boutp (permuted): b1n@W_out + b_out
    const int t = (j >> 2) & 7, g = j >> 5, r = j & 3;
    const int col = 16*t + 4*g + r;
    float s = b_out[col];
    for (int k = 0; k < 128; k++) s = fmaf(ln_b[128 + k], W_out[k*128 + col], s);
    boutp[j] = s;
  }
}

// ---------------- precompute kernel 2 (depends on pre1) ----------------
__global__ __launch_bounds__(128) void pre2(
    const float* __restrict__ emb, const float* __restrict__ W_in,
    const float* __restrict__ ln_g, const float* __restrict__ ln_b,
    const float* __restrict__ WLf, const float* __restrict__ Bnum,
    const float* __restrict__ bfold,
    uint16_t* __restrict__ tcatp, // [2][20][50][64] bf16 slot-major
    uint16_t* __restrict__ wl2p,  // WL1' transposed pack
    float* __restrict__ bf1p,     // bf1' permuted
    uint16_t* __restrict__ a1p)   // A1^T pack, 8-run col map
{
  const int b = blockIdx.x, j = threadIdx.x;
  __shared__ float sh[128];
  if (b < 1000) {                      // Tcat1 = emb@W_in_slice@WL_0, slot-major store
    const int f = b / 50, c = b % 50;
    const float* e  = emb + (f*50 + c)*32;
    const float* wi = W_in + (size_t)f*32*128;
    float s = 0.f;
    for (int k = 0; k < 32; k++) s = fmaf(e[k], wi[k*128 + j], s);
    sh[j] = s;
    __syncthreads();
    float s2 = 0.f;
    for (int k = 0; k < 128; k++) s2 = fmaf(sh[k], WLf[k*128 + j], s2);
    const int t = j >> 4, g = (j >> 2) & 3, r = j & 3;
    const int h = t >> 2, jj = t & 3;
    const int slot = 2*g + (jj >> 1);
    tcatp[((h*20 + f)*50 + c)*64 + slot*8 + (jj & 1)*4 + r] = f2bf(s2);
  } else if (b < 1032) {               // wl2p: WL1' = diag(g0)@WL_1, transposed A-pack
    const int p = b - 1000, t = p >> 2, ks = p & 3;
    const int lane = j & 63, rep = j >> 6;
    const int col = 16*t + (lane & 15);
    const float* wl1 = WLf + 16384;
    for (int ii = 0; ii < 4; ii++) {
      const int i = rep*4 + ii;
      const int k = 32*ks + 8*(lane >> 4) + i;
      wl2p[((t*4 + ks)*64 + lane)*8 + i] = f2bf(ln_g[k] * wl1[k*128 + col]);
    }
  } else if (b == 1032) {              // bf1p (permuted): b0@WL_1 + bfold_1
    const int t = (j >> 2) & 7, g = j >> 5, r = j & 3;
    const int col = 16*t + 4*g + r;
    const float* wl1 = WLf + 16384;
    float s = bfold[128 + col];
    for (int k = 0; k < 128; k++) s = fmaf(ln_b[k], wl1[k*128 + col], s);
    bf1p[j] = s;
  } else {                             // a1p with 8-run col map
    const int t = b - 1033;
    const int lane = j & 63, rep = j >> 6;
    const int p = lane & 15;
    const int col = 32*(t >> 1) + 8*(p >> 2) + 4*(t & 1) + (p & 3);
    for (int ii = 0; ii < 4; ii++) {
      const int i = rep*4 + ii;
      const int k = 8*(lane >> 4) + i;
      float v = 0.f;
      if (k <= 20) {
        if (k == 20) v = bfold[col];
        for (int m = 0; m < 128; m++) v = fmaf(Bnum[k*128 + m], WLf[m*128 + col], v);
      }
      a1p[(t*64 + lane)*8 + i] = f2bf(v);
    }
  }
}

// ---------------- mainK: fused gather + tail, 1 block/CU ----------------
// grid 768 x 512 thr; block owns 128 rows; wave owns 16 rows.
__global__ __launch_bounds__(512, 1) void mainK(
    const uint8_t* __restrict__ idxb,
    const uint16_t* __restrict__ nf,
    const uint16_t* __restrict__ tcatp,
    const uint16_t* __restrict__ a1p,
    const uint16_t* __restrict__ wl2p,
    const uint16_t* __restrict__ woutp,
    const float* __restrict__ bf1p,
    const float* __restrict__ boutp,
    float* __restrict__ out)
{
  __shared__ __align__(16) unsigned char smem[162816];
  uint4* tbl4 = reinterpret_cast<uint4*>(smem);
  const char* tbl = reinterpret_cast<const char*>(smem);
  uint16_t* hst = reinterpret_cast<uint16_t*>(smem + 128000);   // 128 x 136 u16

  const int tid = threadIdx.x, lane = tid & 63, w = tid >> 6;
  const int r8 = lane >> 3, s = lane & 7;
  const int g = lane >> 4, c16 = lane & 15;
  const int bid = blockIdx.x;

  // ====== phases A/B: LDS gather of each column half ======
  for (int h = 0; h < 2; h++) {
    const uint4* src = reinterpret_cast<const uint4*>(tcatp) + h*8000;
    for (int i = tid; i < 8000; i += 512) tbl4[i] = src[i];
    __syncthreads();

    #pragma unroll
    for (int gr = 0; gr < 2; gr++) {
      const int row = w*16 + gr*8 + r8;
      const size_t grow = (size_t)bid*128 + row;
      const uint4 I0 = *reinterpret_cast<const uint4*>(idxb + grow*32);
      const uint4 I1 = *reinterpret_cast<const uint4*>(idxb + grow*32 + 16);
      const uint32_t iw[5] = {I0.x, I0.y, I0.z, I0.w, I1.x};
      uint4 b[20];
      #pragma unroll
      for (int f = 0; f < 20; f++) {
        const int idx = (int)((iw[f >> 2] >> (8*(f & 3))) & 0xffu);
        b[f] = *reinterpret_cast<const uint4*>(tbl + (f*50 + idx)*128 + s*16);
      }
      f32x4 a0 = {0.f,0.f,0.f,0.f}, a1v = {0.f,0.f,0.f,0.f};
      #pragma unroll
      for (int f = 0; f < 20; f++) {
        a0[0] += bflo(b[f].x); a0[1] += bfhi(b[f].x);
        a0[2] += bflo(b[f].y); a0[3] += bfhi(b[f].y);
        a1v[0] += bflo(b[f].z); a1v[1] += bfhi(b[f].z);
        a1v[2] += bflo(b[f].w); a1v[3] += bfhi(b[f].w);
      }
      const uint4 o = { pkbf(a0[0], a0[1]), pkbf(a0[2], a0[3]),
                        pkbf(a1v[0], a1v[1]), pkbf(a1v[2], a1v[3]) };
      *reinterpret_cast<uint4*>(hst + row*136 + 64*h + 8*s) = o;
    }
    __syncthreads();   // reads of this half done (h=0: before restage; h=1: before weights)
  }

  // ====== phase C: stage weights into dead table region ======
  uint16_t* wl2l = reinterpret_cast<uint16_t*>(smem);            // 32768 B
  uint16_t* wol  = reinterpret_cast<uint16_t*>(smem + 32768);    // 32768 B
  uint16_t* a1l  = reinterpret_cast<uint16_t*>(smem + 65536);    //  8192 B
  float*    bf1l = reinterpret_cast<float*>(smem + 73728);       //   512 B
  float*    boll = reinterpret_cast<float*>(smem + 74240);       //   512 B
  uint16_t* hb   = reinterpret_cast<uint16_t*>(smem + 74752) + w*2176;  // 16x136 u16/wave
  {
    uint4* d0 = reinterpret_cast<uint4*>(wl2l);
    const uint4* s0 = reinterpret_cast<const uint4*>(wl2p);
    for (int i = tid; i < 2048; i += 512) d0[i] = s0[i];
    uint4* d1 = reinterpret_cast<uint4*>(wol);
    const uint4* s1 = reinterpret_cast<const uint4*>(woutp);
    for (int i = tid; i < 2048; i += 512) d1[i] = s1[i];
    if (tid < 512) reinterpret_cast<uint4*>(a1l)[tid] = reinterpret_cast<const uint4*>(a1p)[tid];
    if (tid < 32) reinterpret_cast<uint4*>(bf1l)[tid] = reinterpret_cast<const uint4*>(bf1p)[tid];
    else if (tid < 64) reinterpret_cast<uint4*>(boll)[tid - 32] = reinterpret_cast<const uint4*>(boutp)[tid - 32];
  }
  __syncthreads();

  // ====== tail: per wave = 16 rows (r9 tailk body, LDS-sourced) ======
  const int row = w*16 + c16;
  const size_t grow = (size_t)bid*128 + row;

  // numeric fold: acc[t=2ks+hl][r] = cols 32ks+8g+4hl+r
  const short8 xf = *reinterpret_cast<const short8*>(nf + grow*32 + 8*g);
  f32x4 acc[8];
  #pragma unroll
  for (int t = 0; t < 8; t++) {
    const short8 af = *reinterpret_cast<const short8*>(a1l + (t*64 + lane)*8);
    acc[t] = __builtin_amdgcn_mfma_f32_16x16x32_bf16(af, xf, (f32x4){0.f,0.f,0.f,0.f}, 0, 0, 0);
  }

  // add gathered categorical part from hstate (slot-major bf16)
  const uint16_t* h1row = hst + row*136;
  #pragma unroll
  for (int ks = 0; ks < 4; ks++)
    #pragma unroll
    for (int hl = 0; hl < 2; hl++) {
      const int inner = 8*g + 4*hl;
      const int tc = 2*ks + (inner >> 4);
      const int gc = (inner & 15) >> 2;
      const int jj = tc & 3;
      const int P = 64*(tc >> 2) + 8*(2*gc + (jj >> 1)) + 4*(jj & 1);
      const uint2 u = *reinterpret_cast<const uint2*>(h1row + P);
      const int t = 2*ks + hl;
      acc[t][0] += bflo(u.x); acc[t][1] += bfhi(u.x);
      acc[t][2] += bflo(u.y); acc[t][3] += bfhi(u.y);
    }

  // LN0 (gamma/beta folded downstream)
  float sA = 0.f, qA = 0.f;
  #pragma unroll
  for (int t = 0; t < 8; t++)
    #pragma unroll
    for (int r = 0; r < 4; r++) { const float v = acc[t][r]; sA += v; qA = fmaf(v, v, qA); }
  sA += __shfl_xor(sA, 16); sA += __shfl_xor(sA, 32);
  qA += __shfl_xor(qA, 16); qA += __shfl_xor(qA, 32);
  const float mu = sA * (1.f/128.f);
  const float rs = rsqrtf(qA*(1.f/128.f) - mu*mu + LN_EPS);

  short8 a2[4];
  #pragma unroll
  for (int ks = 0; ks < 4; ks++) {
    uint32_t* aw = (uint32_t*)&a2[ks];
    aw[0] = pkbf((acc[2*ks][0]-mu)*rs,   (acc[2*ks][1]-mu)*rs);
    aw[1] = pkbf((acc[2*ks][2]-mu)*rs,   (acc[2*ks][3]-mu)*rs);
    aw[2] = pkbf((acc[2*ks+1][0]-mu)*rs, (acc[2*ks+1][1]-mu)*rs);
    aw[3] = pkbf((acc[2*ks+1][2]-mu)*rs, (acc[2*ks+1][3]-mu)*rs);
  }

  // GEMM2': acc2 = z1 @ WL1' (+bf1')
  f32x4 acc2[8];
  #pragma unroll
  for (int t = 0; t < 8; t++) {
    acc2[t] = *reinterpret_cast<const f32x4*>(bf1l + g*32 + t*4);
    #pragma unroll
    for (int ks = 0; ks < 4; ks++) {
      const short8 wf = *reinterpret_cast<const short8*>(wl2l + ((t*4 + ks)*64 + lane)*8);
      acc2[t] = __builtin_amdgcn_mfma_f32_16x16x32_bf16(wf, a2[ks], acc2[t], 0, 0, 0);
    }
  }

  // LN1
  float s2 = 0.f, q2 = 0.f;
  #pragma unroll
  for (int t = 0; t < 8; t++)
    #pragma unroll
    for (int r = 0; r < 4; r++) { const float v = acc2[t][r]; s2 += v; q2 = fmaf(v, v, q2); }
  s2 += __shfl_xor(s2, 16); s2 += __shfl_xor(s2, 32);
  q2 += __shfl_xor(q2, 16); q2 += __shfl_xor(q2, 32);
  const float mu2 = s2 * (1.f/128.f);
  const float rs2 = rsqrtf(q2*(1.f/128.f) - mu2*mu2 + LN_EPS);

  #pragma unroll
  for (int t = 0; t < 8; t++) {
    const uint32x2 v = { pkbf((acc2[t][0]-mu2)*rs2, (acc2[t][1]-mu2)*rs2),
                         pkbf((acc2[t][2]-mu2)*rs2, (acc2[t][3]-mu2)*rs2) };
    *reinterpret_cast<uint32x2*>(hb + c16*136 + 16*t + 4*g) = v;
  }
  asm volatile("s_waitcnt lgkmcnt(0)" ::: "memory");

  // GEMM3': out = z2 @ Wout' + bout'
  short8 a3[4];
  #pragma unroll
  for (int ks = 0; ks < 4; ks++)
    a3[ks] = *reinterpret_cast<const short8*>(hb + c16*136 + 32*ks + 8*g);
  float* orow = out + grow*128;
  #pragma unroll
  for (int t = 0; t < 8; t++) {
    f32x4 a3c = *reinterpret_cast<const f32x4*>(boll + g*32 + t*4);
    #pragma unroll
    for (int ks = 0; ks < 4; ks++) {
      const short8 wf = *reinterpret_cast<const short8*>(wol + ((t*4 + ks)*64 + lane)*8);
      a3c = __builtin_amdgcn_mfma_f32_16x16x32_bf16(wf, a3[ks], a3c, 0, 0, 0);
    }
    __builtin_nontemporal_store(a3c, reinterpret_cast<f32x4*>(orow + 16*t + 4*g));
  }
}

// ---------------- launcher ----------------
extern "C" void kernel_launch(void* const* d_in, const int* in_sizes, int n_in,
                              void* d_out, int out_size, void* d_ws, size_t ws_size,
                              hipStream_t stream)
{
  const float* x     = (const float*)d_in[0];
  const float* emb   = (const float*)d_in[1];
  const float* W_num = (const float*)d_in[2];
  const float* b_num = (const float*)d_in[3];
  const float* W_in  = (const float*)d_in[4];
  const float* b_in  = (const float*)d_in[5];
  const float* W1    = (const float*)d_in[6];
  const float* b1    = (const float*)d_in[7];
  const float* W2    = (const float*)d_in[8];
  const float* b2    = (const float*)d_in[9];
  const float* ln_g  = (const float*)d_in[10];
  const float* ln_b  = (const float*)d_in[11];
  const float* W_out = (const float*)d_in[12];
  const float* b_out = (const float*)d_in[13];
  float* out = (float*)d_out;

  char* ws = (char*)d_ws;
  float*    WLf   = (float*)(ws + 0);          // 131072 B
  float*    Bnum  = (float*)(ws + 131072);     //  10752 B
  float*    bfold = (float*)(ws + 141824);     //   1024 B
  uint16_t* tcatp = (uint16_t*)(ws + 142848);  // 256000 B
  uint16_t* wl2p  = (uint16_t*)(ws + 398848);  //  32768 B
  uint16_t* woutp = (uint16_t*)(ws + 431616);  //  32768 B
  uint16_t* a1p   = (uint16_t*)(ws + 464384);  //   8192 B
  float*    bf1p  = (float*)(ws + 472576);     //    512 B
  float*    boutp = (float*)(ws + 473088);     //    512 B
  uint8_t*  idxb  = (uint8_t*)(ws + 473600);   // 3145728 B
  uint16_t* nf    = (uint16_t*)(ws + 3619328); // 6291456 B

  xprep<<<dim3(384), dim3(256), 0, stream>>>(x, idxb, nf);
  pre1<<<dim3(312), dim3(128), 0, stream>>>(W_num, b_num, W_in, b_in, W1, b1, W2, b2,
                                            W_out, b_out, ln_g, ln_b,
                                            WLf, Bnum, bfold, woutp, boutp);
  pre2<<<dim3(1041), dim3(128), 0, stream>>>(emb, W_in, ln_g, ln_b, WLf, Bnum, bfold,
                                             tcatp, wl2p, bf1p, a1p);
  mainK<<<dim3(768), dim3(512), 0, stream>>>(idxb, nf, tcatp, a1p, wl2p, woutp,
                                             bf1p, boutp, out);
}

// Round 11
// 69.926 us; speedup vs baseline: 1.5221x; 1.3786x over previous
//
#include <hip/hip_runtime.h>
#include <hip/hip_bf16.h>
#include <stdint.h>
#include <stddef.h>

// ---------------------------------------------------------------------------
// FixedEmbedderNN — round 11: r10's fused mainK widened to 1024 threads
// (16 waves = 4 waves/SIMD for latency hiding), xprep folded into mainK.
//  LDS union (162,816 B):
//    phase A/B: [0,128000) half-table + [128000,162816) hstate (128x136 u16)
//    phase C  : [0,32768) wl2l, [32768,65536) wol, [65536,73728) a1l,
//               [73728,74240) bf1l, [74240,74752) boll,
//               [74752,109568) hbuf (8 tail waves x 4352B). hstate persists.
//  Gather: wave w (0..15) owns rows w*8..w*8+8; lane=(r8,s); idx words packed
//  once in 5 VGPRs (reused across halves); 20 ds_read_b128 per wave per half.
//  Tail: waves 0..7, 16 rows each — identical math/mappings to r9/r10
//  (verified): a1p 8-run col map, hstate P-formula, GEMM2'->LN1->GEMM3'.
// ---------------------------------------------------------------------------

typedef __attribute__((ext_vector_type(8))) short short8;
typedef __attribute__((ext_vector_type(4))) float f32x4;
typedef __attribute__((ext_vector_type(2))) uint32_t uint32x2;

#define LN_EPS 1e-5f

__device__ __forceinline__ float bflo(uint32_t u){ union{uint32_t u;float f;} c; c.u = u<<16; return c.f; }
__device__ __forceinline__ float bfhi(uint32_t u){ union{uint32_t u;float f;} c; c.u = u&0xffff0000u; return c.f; }
__device__ __forceinline__ uint16_t f2bf(float f){
  union{ __hip_bfloat16 h; uint16_t u; } c; c.h = __float2bfloat16(f); return c.u;
}
__device__ __forceinline__ uint32_t pkbf(float lo, float hi){
  return (uint32_t)f2bf(lo) | ((uint32_t)f2bf(hi)<<16);
}

// ---------------- precompute kernel 1 (no deps) ----------------
__global__ __launch_bounds__(128) void pre1(
    const float* __restrict__ W_num, const float* __restrict__ b_num,
    const float* __restrict__ W_in,  const float* __restrict__ b_in,
    const float* __restrict__ W1,    const float* __restrict__ b1,
    const float* __restrict__ W2,    const float* __restrict__ b2,
    const float* __restrict__ W_out, const float* __restrict__ b_out,
    const float* __restrict__ ln_g,  const float* __restrict__ ln_b,
    float* __restrict__ WLf,    // [2][128][128]
    float* __restrict__ Bnum,   // [21][128]
    float* __restrict__ bfold,  // [2][128]
    uint16_t* __restrict__ woutp, // Wout' transposed pack
    float* __restrict__ boutp)    // bout' permuted [g*32+t*4+r]
{
  const int b = blockIdx.x, j = threadIdx.x;
  if (b < 256) {                       // WL = W1@W2 per layer (4-way ILP)
    const int l = b >> 7, k = b & 127;
    const float* w1r = W1 + (l*128 + k)*256;
    const float* w2  = W2 + l*256*128;
    float sa = 0.f, sb = 0.f, sc = 0.f, sd = 0.f;
    for (int m = 0; m < 256; m += 4) {
      sa = fmaf(w1r[m],   w2[m*128 + j],       sa);
      sb = fmaf(w1r[m+1], w2[(m+1)*128 + j],   sb);
      sc = fmaf(w1r[m+2], w2[(m+2)*128 + j],   sc);
      sd = fmaf(w1r[m+3], w2[(m+3)*128 + j],   sd);
    }
    WLf[(l*128 + k)*128 + j] = (sa + sb) + (sc + sd);
  } else if (b < 277) {                // Bnum rows
    const int r = b - 256;
    if (r < 20) {
      const float* wn = W_num + r*32;
      const float* wi = W_in + (size_t)(20 + r)*32*128;
      float s = 0.f;
      for (int e = 0; e < 32; e++) s = fmaf(wn[e], wi[e*128 + j], s);
      Bnum[r*128 + j] = s;
    } else {
      float s = b_in[j];
      for (int f = 0; f < 20; f++) {
        const float* bn = b_num + f*32;
        const float* wi = W_in + (size_t)(20 + f)*32*128;
        for (int e = 0; e < 32; e++) s = fmaf(bn[e], wi[e*128 + j], s);
      }
      Bnum[20*128 + j] = s;
    }
  } else if (b < 279) {                // bfold = b1@W2 + b2
    const int l = b - 277;
    const float* b1r = b1 + l*256;
    const float* w2  = W2 + l*256*128;
    float s = b2[l*128 + j];
    for (int k = 0; k < 256; k++) s = fmaf(b1r[k], w2[k*128 + j], s);
    bfold[l*128 + j] = s;
  } else if (b < 311) {                // woutp: Wout' = diag(g1)@W_out, transposed A-pack
    const int p = b - 279, t = p >> 2, ks = p & 3;
    const int lane = j & 63, rep = j >> 6;
    const int col = 16*t + (lane & 15);
    for (int ii = 0; ii < 4; ii++) {
      const int i = rep*4 + ii;
      const int k = 32*ks + 8*(lane >> 4) + i;
      woutp[((t*4 + ks)*64 + lane)*8 + i] = f2bf(ln_g[128 + k] * W_out[k*128 + col]);
    }
  } else {                             // boutp (permuted): b1n@W_out + b_out
    const int t = (j >> 2) & 7, g = j >> 5, r = j & 3;
    const int col = 16*t + 4*g + r;
    float s = b_out[col];
    for (int k = 0; k < 128; k++) s = fmaf(ln_b[128 + k], W_out[k*128 + col], s);
    boutp[j] = s;
  }
}

// ---------------- precompute kernel 2 (depends on pre1) ----------------
__global__ __launch_bounds__(128) void pre2(
    const float* __restrict__ emb, const float* __restrict__ W_in,
    const float* __restrict__ ln_g, const float* __restrict__ ln_b,
    const float* __restrict__ WLf, const float* __restrict__ Bnum,
    const float* __restrict__ bfold,
    uint16_t* __restrict__ tcatp, // [2][20][50][64] bf16 slot-major
    uint16_t* __restrict__ wl2p,  // WL1' transposed pack
    float* __restrict__ bf1p,     // bf1' permuted
    uint16_t* __restrict__ a1p)   // A1^T pack, 8-run col map
{
  const int b = blockIdx.x, j = threadIdx.x;
  __shared__ float sh[128];
  if (b < 1000) {                      // Tcat1 = emb@W_in_slice@WL_0, slot-major store
    const int f = b / 50, c = b % 50;
    const float* e  = emb + (f*50 + c)*32;
    const float* wi = W_in + (size_t)f*32*128;
    float s = 0.f;
    for (int k = 0; k < 32; k++) s = fmaf(e[k], wi[k*128 + j], s);
    sh[j] = s;
    __syncthreads();
    float sa = 0.f, sb = 0.f, sc = 0.f, sd = 0.f;    // 4-way ILP
    for (int k = 0; k < 128; k += 4) {
      sa = fmaf(sh[k],   WLf[k*128 + j],       sa);
      sb = fmaf(sh[k+1], WLf[(k+1)*128 + j],   sb);
      sc = fmaf(sh[k+2], WLf[(k+2)*128 + j],   sc);
      sd = fmaf(sh[k+3], WLf[(k+3)*128 + j],   sd);
    }
    const float s2 = (sa + sb) + (sc + sd);
    const int t = j >> 4, g = (j >> 2) & 3, r = j & 3;
    const int h = t >> 2, jj = t & 3;
    const int slot = 2*g + (jj >> 1);
    tcatp[((h*20 + f)*50 + c)*64 + slot*8 + (jj & 1)*4 + r] = f2bf(s2);
  } else if (b < 1032) {               // wl2p: WL1' = diag(g0)@WL_1, transposed A-pack
    const int p = b - 1000, t = p >> 2, ks = p & 3;
    const int lane = j & 63, rep = j >> 6;
    const int col = 16*t + (lane & 15);
    const float* wl1 = WLf + 16384;
    for (int ii = 0; ii < 4; ii++) {
      const int i = rep*4 + ii;
      const int k = 32*ks + 8*(lane >> 4) + i;
      wl2p[((t*4 + ks)*64 + lane)*8 + i] = f2bf(ln_g[k] * wl1[k*128 + col]);
    }
  } else if (b == 1032) {              // bf1p (permuted): b0@WL_1 + bfold_1
    const int t = (j >> 2) & 7, g = j >> 5, r = j & 3;
    const int col = 16*t + 4*g + r;
    const float* wl1 = WLf + 16384;
    float s = bfold[128 + col];
    for (int k = 0; k < 128; k++) s = fmaf(ln_b[k], wl1[k*128 + col], s);
    bf1p[j] = s;
  } else {                             // a1p with 8-run col map (4-way ILP)
    const int t = b - 1033;
    const int lane = j & 63, rep = j >> 6;
    const int p = lane & 15;
    const int col = 32*(t >> 1) + 8*(p >> 2) + 4*(t & 1) + (p & 3);
    for (int ii = 0; ii < 4; ii++) {
      const int i = rep*4 + ii;
      const int k = 8*(lane >> 4) + i;
      float v = 0.f;
      if (k <= 20) {
        if (k == 20) v = bfold[col];
        float va = 0.f, vb = 0.f, vc = 0.f, vd = 0.f;
        for (int m = 0; m < 128; m += 4) {
          va = fmaf(Bnum[k*128 + m],   WLf[m*128 + col],       va);
          vb = fmaf(Bnum[k*128 + m+1], WLf[(m+1)*128 + col],   vb);
          vc = fmaf(Bnum[k*128 + m+2], WLf[(m+2)*128 + col],   vc);
          vd = fmaf(Bnum[k*128 + m+3], WLf[(m+3)*128 + col],   vd);
        }
        v += (va + vb) + (vc + vd);
      }
      a1p[(t*64 + lane)*8 + i] = f2bf(v);
    }
  }
}

// ---------------- mainK: fused gather + tail, 1024 thr, 1 block/CU ----------
// grid 768; block owns 128 rows. Gather: 16 waves x 8 rows. Tail: 8 waves x 16.
__global__ __launch_bounds__(1024, 1) void mainK(
    const float* __restrict__ x,
    const uint16_t* __restrict__ tcatp,
    const uint16_t* __restrict__ a1p,
    const uint16_t* __restrict__ wl2p,
    const uint16_t* __restrict__ woutp,
    const float* __restrict__ bf1p,
    const float* __restrict__ boutp,
    float* __restrict__ out)
{
  __shared__ __align__(16) unsigned char smem[162816];
  uint4* tbl4 = reinterpret_cast<uint4*>(smem);
  const char* tbl = reinterpret_cast<const char*>(smem);
  uint16_t* hst = reinterpret_cast<uint16_t*>(smem + 128000);   // 128 x 136 u16

  const int tid = threadIdx.x, lane = tid & 63, w = tid >> 6;   // w in 0..15
  const int r8 = lane >> 3, s = lane & 7;
  const int bid = blockIdx.x;

  // ---- pack this wave-row's 20 categorical codes (8 dup lanes share lines) ----
  const int myrow = w*8 + r8;
  uint32_t iw0, iw1, iw2, iw3, iw4;
  {
    const float* xr = x + ((size_t)bid*128 + myrow)*40;
    const f32x4 c0 = *reinterpret_cast<const f32x4*>(xr);
    const f32x4 c1 = *reinterpret_cast<const f32x4*>(xr + 4);
    const f32x4 c2 = *reinterpret_cast<const f32x4*>(xr + 8);
    const f32x4 c3 = *reinterpret_cast<const f32x4*>(xr + 12);
    const f32x4 c4 = *reinterpret_cast<const f32x4*>(xr + 16);
    iw0 = (uint32_t)c0[0] | ((uint32_t)c0[1]<<8) | ((uint32_t)c0[2]<<16) | ((uint32_t)c0[3]<<24);
    iw1 = (uint32_t)c1[0] | ((uint32_t)c1[1]<<8) | ((uint32_t)c1[2]<<16) | ((uint32_t)c1[3]<<24);
    iw2 = (uint32_t)c2[0] | ((uint32_t)c2[1]<<8) | ((uint32_t)c2[2]<<16) | ((uint32_t)c2[3]<<24);
    iw3 = (uint32_t)c3[0] | ((uint32_t)c3[1]<<8) | ((uint32_t)c3[2]<<16) | ((uint32_t)c3[3]<<24);
    iw4 = (uint32_t)c4[0] | ((uint32_t)c4[1]<<8) | ((uint32_t)c4[2]<<16) | ((uint32_t)c4[3]<<24);
  }

  // ====== phases A/B: LDS gather of each column half ======
  for (int h = 0; h < 2; h++) {
    const uint4* src = reinterpret_cast<const uint4*>(tcatp) + h*8000;
    for (int i = tid; i < 8000; i += 1024) tbl4[i] = src[i];
    __syncthreads();

    const uint32_t iw[5] = {iw0, iw1, iw2, iw3, iw4};
    uint4 b[20];
    #pragma unroll
    for (int f = 0; f < 20; f++) {
      const int idx = (int)((iw[f >> 2] >> (8*(f & 3))) & 0xffu);
      b[f] = *reinterpret_cast<const uint4*>(tbl + (f*50 + idx)*128 + s*16);
    }
    f32x4 a0 = {0.f,0.f,0.f,0.f}, a1v = {0.f,0.f,0.f,0.f};
    #pragma unroll
    for (int f = 0; f < 20; f++) {
      a0[0] += bflo(b[f].x); a0[1] += bfhi(b[f].x);
      a0[2] += bflo(b[f].y); a0[3] += bfhi(b[f].y);
      a1v[0] += bflo(b[f].z); a1v[1] += bfhi(b[f].z);
      a1v[2] += bflo(b[f].w); a1v[3] += bfhi(b[f].w);
    }
    const uint4 o = { pkbf(a0[0], a0[1]), pkbf(a0[2], a0[3]),
                      pkbf(a1v[0], a1v[1]), pkbf(a1v[2], a1v[3]) };
    *reinterpret_cast<uint4*>(hst + myrow*136 + 64*h + 8*s) = o;
    __syncthreads();
  }

  // ====== phase C: stage weights into dead table region ======
  uint16_t* wl2l = reinterpret_cast<uint16_t*>(smem);            // 32768 B
  uint16_t* wol  = reinterpret_cast<uint16_t*>(smem + 32768);    // 32768 B
  uint16_t* a1l  = reinterpret_cast<uint16_t*>(smem + 65536);    //  8192 B
  float*    bf1l = reinterpret_cast<float*>(smem + 73728);       //   512 B
  float*    boll = reinterpret_cast<float*>(smem + 74240);       //   512 B
  {
    uint4* d0 = reinterpret_cast<uint4*>(wl2l);
    const uint4* s0 = reinterpret_cast<const uint4*>(wl2p);
    for (int i = tid; i < 2048; i += 1024) d0[i] = s0[i];
    uint4* d1 = reinterpret_cast<uint4*>(wol);
    const uint4* s1 = reinterpret_cast<const uint4*>(woutp);
    for (int i = tid; i < 2048; i += 1024) d1[i] = s1[i];
    if (tid < 512) reinterpret_cast<uint4*>(a1l)[tid] = reinterpret_cast<const uint4*>(a1p)[tid];
    else if (tid < 544) reinterpret_cast<uint4*>(bf1l)[tid - 512] = reinterpret_cast<const uint4*>(bf1p)[tid - 512];
    else if (tid < 576) reinterpret_cast<uint4*>(boll)[tid - 544] = reinterpret_cast<const uint4*>(boutp)[tid - 544];
  }
  __syncthreads();

  // ====== tail: waves 0..7, 16 rows each (r9/r10 verified body) ======
  if (w < 8) {
    uint16_t* hb = reinterpret_cast<uint16_t*>(smem + 74752) + w*2176;  // 16x136 u16
    const int g = lane >> 4, c16 = lane & 15;
    const int row = w*16 + c16;
    const size_t grow = (size_t)bid*128 + row;

    // numeric bf16 fragment from x (lane-local; rows k>20 hit zero a1p rows)
    short8 xf;
    {
      uint32_t* xw = (uint32_t*)&xf;
      const float* xn = x + grow*40 + 20;
      if (g < 2) {
        const f32x4 a = *reinterpret_cast<const f32x4*>(xn + 8*g);
        const f32x4 b = *reinterpret_cast<const f32x4*>(xn + 8*g + 4);
        xw[0] = pkbf(a[0], a[1]); xw[1] = pkbf(a[2], a[3]);
        xw[2] = pkbf(b[0], b[1]); xw[3] = pkbf(b[2], b[3]);
      } else if (g == 2) {
        const f32x4 a = *reinterpret_cast<const f32x4*>(xn + 16);
        xw[0] = pkbf(a[0], a[1]); xw[1] = pkbf(a[2], a[3]);
        xw[2] = pkbf(1.0f, 0.0f); xw[3] = 0;
      } else {
        xw[0] = 0; xw[1] = 0; xw[2] = 0; xw[3] = 0;
      }
    }

    // numeric fold: acc[t=2ks+hl][r] = cols 32ks+8g+4hl+r
    f32x4 acc[8];
    #pragma unroll
    for (int t = 0; t < 8; t++) {
      const short8 af = *reinterpret_cast<const short8*>(a1l + (t*64 + lane)*8);
      acc[t] = __builtin_amdgcn_mfma_f32_16x16x32_bf16(af, xf, (f32x4){0.f,0.f,0.f,0.f}, 0, 0, 0);
    }

    // add gathered categorical part from hstate (slot-major bf16)
    const uint16_t* h1row = hst + row*136;
    #pragma unroll
    for (int ks = 0; ks < 4; ks++)
      #pragma unroll
      for (int hl = 0; hl < 2; hl++) {
        const int inner = 8*g + 4*hl;
        const int tc = 2*ks + (inner >> 4);
        const int gc = (inner & 15) >> 2;
        const int jj = tc & 3;
        const int P = 64*(tc >> 2) + 8*(2*gc + (jj >> 1)) + 4*(jj & 1);
        const uint2 u = *reinterpret_cast<const uint2*>(h1row + P);
        const int t = 2*ks + hl;
        acc[t][0] += bflo(u.x); acc[t][1] += bfhi(u.x);
        acc[t][2] += bflo(u.y); acc[t][3] += bfhi(u.y);
      }

    // LN0 (gamma/beta folded downstream)
    float sA = 0.f, qA = 0.f;
    #pragma unroll
    for (int t = 0; t < 8; t++)
      #pragma unroll
      for (int r = 0; r < 4; r++) { const float v = acc[t][r]; sA += v; qA = fmaf(v, v, qA); }
    sA += __shfl_xor(sA, 16); sA += __shfl_xor(sA, 32);
    qA += __shfl_xor(qA, 16); qA += __shfl_xor(qA, 32);
    const float mu = sA * (1.f/128.f);
    const float rs = rsqrtf(qA*(1.f/128.f) - mu*mu + LN_EPS);

    short8 a2[4];
    #pragma unroll
    for (int ks = 0; ks < 4; ks++) {
      uint32_t* aw = (uint32_t*)&a2[ks];
      aw[0] = pkbf((acc[2*ks][0]-mu)*rs,   (acc[2*ks][1]-mu)*rs);
      aw[1] = pkbf((acc[2*ks][2]-mu)*rs,   (acc[2*ks][3]-mu)*rs);
      aw[2] = pkbf((acc[2*ks+1][0]-mu)*rs, (acc[2*ks+1][1]-mu)*rs);
      aw[3] = pkbf((acc[2*ks+1][2]-mu)*rs, (acc[2*ks+1][3]-mu)*rs);
    }

    // GEMM2': acc2 = z1 @ WL1' (+bf1')
    f32x4 acc2[8];
    #pragma unroll
    for (int t = 0; t < 8; t++) {
      acc2[t] = *reinterpret_cast<const f32x4*>(bf1l + ((lane >> 4))*32 + t*4);
      #pragma unroll
      for (int ks = 0; ks < 4; ks++) {
        const short8 wf = *reinterpret_cast<const short8*>(wl2l + ((t*4 + ks)*64 + lane)*8);
        acc2[t] = __builtin_amdgcn_mfma_f32_16x16x32_bf16(wf, a2[ks], acc2[t], 0, 0, 0);
      }
    }

    // LN1
    float s2 = 0.f, q2 = 0.f;
    #pragma unroll
    for (int t = 0; t < 8; t++)
      #pragma unroll
      for (int r = 0; r < 4; r++) { const float v = acc2[t][r]; s2 += v; q2 = fmaf(v, v, q2); }
    s2 += __shfl_xor(s2, 16); s2 += __shfl_xor(s2, 32);
    q2 += __shfl_xor(q2, 16); q2 += __shfl_xor(q2, 32);
    const float mu2 = s2 * (1.f/128.f);
    const float rs2 = rsqrtf(q2*(1.f/128.f) - mu2*mu2 + LN_EPS);

    #pragma unroll
    for (int t = 0; t < 8; t++) {
      const uint32x2 v = { pkbf((acc2[t][0]-mu2)*rs2, (acc2[t][1]-mu2)*rs2),
                           pkbf((acc2[t][2]-mu2)*rs2, (acc2[t][3]-mu2)*rs2) };
      *reinterpret_cast<uint32x2*>(hb + c16*136 + 16*t + 4*g) = v;
    }
    asm volatile("s_waitcnt lgkmcnt(0)" ::: "memory");

    // GEMM3': out = z2 @ Wout' + bout'
    short8 a3[4];
    #pragma unroll
    for (int ks = 0; ks < 4; ks++)
      a3[ks] = *reinterpret_cast<const short8*>(hb + c16*136 + 32*ks + 8*g);
    float* orow = out + grow*128;
    #pragma unroll
    for (int t = 0; t < 8; t++) {
      f32x4 a3c = *reinterpret_cast<const f32x4*>(boll + g*32 + t*4);
      #pragma unroll
      for (int ks = 0; ks < 4; ks++) {
        const short8 wf = *reinterpret_cast<const short8*>(wol + ((t*4 + ks)*64 + lane)*8);
        a3c = __builtin_amdgcn_mfma_f32_16x16x32_bf16(wf, a3[ks], a3c, 0, 0, 0);
      }
      __builtin_nontemporal_store(a3c, reinterpret_cast<f32x4*>(orow + 16*t + 4*g));
    }
  }
}

// ---------------- launcher ----------------
extern "C" void kernel_launch(void* const* d_in, const int* in_sizes, int n_in,
                              void* d_out, int out_size, void* d_ws, size_t ws_size,
                              hipStream_t stream)
{
  const float* x     = (const float*)d_in[0];
  const float* emb   = (const float*)d_in[1];
  const float* W_num = (const float*)d_in[2];
  const float* b_num = (const float*)d_in[3];
  const float* W_in  = (const float*)d_in[4];
  const float* b_in  = (const float*)d_in[5];
  const float* W1    = (const float*)d_in[6];
  const float* b1    = (const float*)d_in[7];
  const float* W2    = (const float*)d_in[8];
  const float* b2    = (const float*)d_in[9];
  const float* ln_g  = (const float*)d_in[10];
  const float* ln_b  = (const float*)d_in[11];
  const float* W_out = (const float*)d_in[12];
  const float* b_out = (const float*)d_in[13];
  float* out = (float*)d_out;

  char* ws = (char*)d_ws;
  float*    WLf   = (float*)(ws + 0);          // 131072 B
  float*    Bnum  = (float*)(ws + 131072);     //  10752 B
  float*    bfold = (float*)(ws + 141824);     //   1024 B
  uint16_t* tcatp = (uint16_t*)(ws + 142848);  // 256000 B
  uint16_t* wl2p  = (uint16_t*)(ws + 398848);  //  32768 B
  uint16_t* woutp = (uint16_t*)(ws + 431616);  //  32768 B
  uint16_t* a1p   = (uint16_t*)(ws + 464384);  //   8192 B
  float*    bf1p  = (float*)(ws + 472576);     //    512 B
  float*    boutp = (float*)(ws + 473088);     //    512 B

  pre1<<<dim3(312), dim3(128), 0, stream>>>(W_num, b_num, W_in, b_in, W1, b1, W2, b2,
                                            W_out, b_out, ln_g, ln_b,
                                            WLf, Bnum, bfold, woutp, boutp);
  pre2<<<dim3(1041), dim3(128), 0, stream>>>(emb, W_in, ln_g, ln_b, WLf, Bnum, bfold,
                                             tcatp, wl2p, bf1p, a1p);
  mainK<<<dim3(768), dim3(1024), 0, stream>>>(x, tcatp, a1p, wl2p, woutp,
                                              bf1p, boutp, out);
}